// Round 14
// baseline (1299.244 us; speedup 1.0000x reference)
//
#include <hip/hip_runtime.h>

#define N_NODES 100000
#define E_EDGES 800000
#define E_TOT   900000
#define F 512

typedef __attribute__((ext_vector_type(8))) short short8;
typedef __attribute__((ext_vector_type(4))) float f32x4;
typedef unsigned int u32;

__device__ __forceinline__ float bfu(unsigned int u) {
    union { unsigned int i; float f; } c; c.i = u << 16; return c.f;
}
__device__ __forceinline__ unsigned short f2b(float f) {
    union { float f; unsigned int u; } c; c.f = f;
    return (unsigned short)((c.u + 0x7fffu + ((c.u >> 16) & 1u)) >> 16);
}
__device__ __forceinline__ float fbits(unsigned int u) {
    union { unsigned int i; float f; } c; c.i = u; return c.f;
}
__device__ __forceinline__ unsigned int bits(float f) {
    union { float f; unsigned int i; } c; c.f = f; return c.i;
}
__device__ __forceinline__ void gload_lds16(const void* g, void* l) {
    __builtin_amdgcn_global_load_lds(
        (const __attribute__((address_space(1))) u32*)g,
        (__attribute__((address_space(3))) u32*)l, 16, 0, 0);
}

// ---- CSR build ----
__global__ void k_init(unsigned int* deg, unsigned int* counter, unsigned int* dcnt) {
    int i = blockIdx.x * 256 + threadIdx.x;
    if (i < N_NODES) deg[i] = 1u;           // self loop
    if (i == 0) *counter = 0u;
    if (blockIdx.x == 0 && threadIdx.x < 64) dcnt[threadIdx.x] = 0u;
}

__global__ void k_hist(const int* __restrict__ ei, unsigned int* deg) {
    int e = blockIdx.x * 256 + threadIdx.x;
    if (e < E_EDGES) atomicAdd(&deg[ei[E_EDGES + e]], 1u);
}

__global__ void k_disalloc(const unsigned int* __restrict__ deg, unsigned int* counter,
                           float* __restrict__ dis,
                           int2* __restrict__ seg, unsigned int* __restrict__ cursor,
                           unsigned int* __restrict__ dcnt) {
    int i = blockIdx.x * 256 + threadIdx.x;
    if (i < N_NODES) {
        unsigned int d = deg[i];
        dis[i] = rsqrtf((float)d);
        unsigned int p = atomicAdd(counter, d);
        seg[i] = make_int2((int)p, (int)(p + d));
        cursor[i] = p;
        atomicAdd(&dcnt[d < 63u ? d : 63u], 1u);   // degree histogram
    }
}

// exclusive scan of 64 degree buckets -> bucket cursors
__global__ void k_dscan(const unsigned int* __restrict__ dcnt, unsigned int* __restrict__ dcur) {
    __shared__ unsigned int s[64];
    int b = threadIdx.x;
    s[b] = dcnt[b];
    __syncthreads();
    if (b == 0) {
        unsigned int run = 0;
        for (int i = 0; i < 64; ++i) { unsigned int c = s[i]; s[i] = run; run += c; }
    }
    __syncthreads();
    dcur[b] = s[b];
}

// scatter node ids into degree-sorted permutation
__global__ void k_dperm(const unsigned int* __restrict__ deg, unsigned int* __restrict__ dcur,
                        int* __restrict__ perm) {
    int i = blockIdx.x * 256 + threadIdx.x;
    if (i < N_NODES) {
        unsigned int d = deg[i];
        unsigned int b = d < 63u ? d : 63u;
        unsigned int slot = atomicAdd(&dcur[b], 1u);
        perm[slot] = i;
    }
}

__global__ void k_scatter(const int* __restrict__ ei, const float* __restrict__ dis,
                          unsigned int* __restrict__ cursor,
                          uint2* __restrict__ ev) {
    int e = blockIdx.x * 256 + threadIdx.x;
    if (e < E_TOT) {
        int s, d;
        if (e < E_EDGES) { s = ei[e]; d = ei[E_EDGES + e]; }
        else             { s = e - E_EDGES; d = s; }
        unsigned int p = atomicAdd(&cursor[d], 1u);
        ev[p] = make_uint2((unsigned)s, bits(dis[s] * dis[d]));
    }
}

// ---- dtype converts ----
__global__ void k_cvtX(const float* __restrict__ xin, unsigned short* __restrict__ xb) {
    int i = blockIdx.x * 256 + threadIdx.x;
    const f32x4* p = (const f32x4*)xin + (size_t)i * 2;
    f32x4 a = __builtin_nontemporal_load(p);
    f32x4 b = __builtin_nontemporal_load(p + 1);
    uint4 o;
    o.x = (unsigned)f2b(a[0]) | ((unsigned)f2b(a[1]) << 16);
    o.y = (unsigned)f2b(a[2]) | ((unsigned)f2b(a[3]) << 16);
    o.z = (unsigned)f2b(b[0]) | ((unsigned)f2b(b[1]) << 16);
    o.w = (unsigned)f2b(b[2]) | ((unsigned)f2b(b[3]) << 16);
    *(uint4*)(xb + (size_t)i * 8) = o;
}

__global__ void k_cvtW(const float* __restrict__ W1, const float* __restrict__ W2,
                       unsigned short* __restrict__ W1t, unsigned short* __restrict__ W2t) {
    int t = blockIdx.x * 256 + threadIdx.x;
    int which = t >= F * F;
    int u = t - which * F * F;
    int n = u >> 9, k = u & 511;
    const float* W = which ? W2 : W1;
    unsigned short* Wt = which ? W2t : W1t;
    Wt[u] = f2b(W[k * F + n]);
}

// ---- GEMM 256x128, BK=32, 2-phase dbuf, 48 KB LDS -> 2 blocks/CU ----
__global__ __launch_bounds__(512, 4)
void gemm_bt(const unsigned short* __restrict__ A, const unsigned short* __restrict__ Bt,
             const float* __restrict__ bias,
             unsigned short* __restrict__ outb, float* __restrict__ outf,
             int relu, int M) {
    __shared__ unsigned short sm[24576];  // 48 KB: A0@0, A1@8192, B0@16384, B1@20480

    // bijective XCD remap: 4 N-siblings of one A-slab -> same XCD, adjacent
    int nwg = gridDim.x * gridDim.y;              // 1564
    int orig = blockIdx.y * gridDim.x + blockIdx.x;
    int q = nwg >> 3, r = nwg & 7;
    int xcd = orig & 7, j8 = orig >> 3;
    int wgid = (xcd < r ? xcd * (q + 1) : r * (q + 1) + (xcd - r) * q) + j8;
    int by = wgid & 3;                            // N tile (0..3), 128 cols
    int bx = wgid >> 2;                           // M tile (0..390)

    int t  = threadIdx.x;
    int lane = t & 63, w = t >> 6;
    int wr = w >> 1, wc = w & 1;
    int rsel = lane & 15, khalf = (lane >> 4) * 8;

    f32x4 acc[4][4];
    #pragma unroll
    for (int m = 0; m < 4; ++m)
        #pragma unroll
        for (int n = 0; n < 4; ++n)
            acc[m][n] = (f32x4){0.f, 0.f, 0.f, 0.f};

    int rowBase = bx * 256;

    int arA[2], kcA[2];
    #pragma unroll
    for (int i = 0; i < 2; ++i) {
        int idx = i * 512 + t;
        int rr = idx >> 2;
        kcA[i] = (idx & 3) * 8;
        int ga = rowBase + rr; if (ga >= M) ga = M - 1;
        arA[i] = ga;
    }
    int brB = by * 128 + (t >> 2);
    int kcB = (t & 3) * 8;

    auto STAGE = [&](int buf, int k0) {
        gload_lds16(A + (size_t)arA[0] * F + k0 + kcA[0], sm + buf * 8192 + t * 8);
        gload_lds16(A + (size_t)arA[1] * F + k0 + kcA[1], sm + buf * 8192 + (512 + t) * 8);
        gload_lds16(Bt + (size_t)brB * F + k0 + kcB, sm + 16384 + buf * 4096 + t * 8);
    };
    auto COMPUTE = [&](int buf) {
        const unsigned short* la = sm + buf * 8192;
        const unsigned short* lb = sm + 16384 + buf * 4096;
        short8 bfr[4];
        #pragma unroll
        for (int n = 0; n < 4; ++n)
            bfr[n] = *(const short8*)&lb[(wc * 64 + n * 16 + rsel) * 32 + khalf];
        #pragma unroll
        for (int m = 0; m < 4; ++m) {
            short8 af = *(const short8*)&la[(wr * 64 + m * 16 + rsel) * 32 + khalf];
            #pragma unroll
            for (int n = 0; n < 4; ++n)
                acc[m][n] = __builtin_amdgcn_mfma_f32_16x16x32_bf16(af, bfr[n], acc[m][n], 0, 0, 0);
        }
    };

    STAGE(0, 0);
    __syncthreads();
    #pragma unroll
    for (int kp = 0; kp < 8; ++kp) {
        STAGE(1, (2 * kp + 1) * 32);
        COMPUTE(0);
        __syncthreads();
        if (kp < 7) STAGE(0, (2 * kp + 2) * 32);
        COMPUTE(1);
        __syncthreads();
    }

    int rq = (lane >> 4) * 4, cq = lane & 15;
    if (outb) {
        // restage bf16 C-tile through LDS in two 128x128 halves
        #pragma unroll
        for (int h = 0; h < 2; ++h) {
            if (h) __syncthreads();
            if ((wr >> 1) == h) {
                #pragma unroll
                for (int m = 0; m < 4; ++m)
                    #pragma unroll
                    for (int n = 0; n < 4; ++n) {
                        int cl = wc * 64 + n * 16 + cq;
                        float bv = bias[by * 128 + cl];
                        #pragma unroll
                        for (int j = 0; j < 4; ++j) {
                            int rl = (wr & 1) * 64 + m * 16 + rq + j;
                            float v = acc[m][n][j] + bv;
                            if (relu) v = fmaxf(v, 0.f);
                            sm[rl * 128 + cl] = f2b(v);
                        }
                    }
            }
            __syncthreads();
            #pragma unroll
            for (int p = 0; p < 4; ++p) {
                int sidx = (p * 512 + t) * 8;
                int row = sidx >> 7;
                int col = sidx & 127;
                int grow = rowBase + h * 128 + row;
                if (grow < M) {
                    uint4 v = *(const uint4*)&sm[sidx];
                    *(uint4*)&outb[(size_t)grow * F + by * 128 + col] = v;
                }
            }
        }
    } else {
        #pragma unroll
        for (int m = 0; m < 4; ++m)
            #pragma unroll
            for (int n = 0; n < 4; ++n) {
                int colv = by * 128 + wc * 64 + n * 16 + cq;
                float bv = bias[colv];
                #pragma unroll
                for (int j = 0; j < 4; ++j) {
                    int row = rowBase + wr * 64 + m * 16 + rq + j;
                    if (row < M) {
                        float v = acc[m][n][j] + bv;
                        if (relu) v = fmaxf(v, 0.f);
                        __builtin_nontemporal_store(v, outf + (size_t)row * F + colv);
                    }
                }
            }
    }
}

// ---- aggregation: g[d] = sum_e val[e] * hin[col[e]]  (512-wide, x8 unroll) ----
// Nodes processed in degree-sorted order (perm): the 4 waves of a block get
// equal-degree nodes -> finish together -> no ragged wave-slot tail.
#define LOADP(k) uint2 p##k = ev[e + k]
#define LOADV(k) uint4 v##k = *(const uint4*)(base + ((size_t)p##k.x << 9))
#define ACCV(k)  { float w_ = fbits(p##k.y); \
    acc[0] += w_ * bfu(v##k.x & 0xffffu); acc[1] += w_ * bfu(v##k.x >> 16); \
    acc[2] += w_ * bfu(v##k.y & 0xffffu); acc[3] += w_ * bfu(v##k.y >> 16); \
    acc[4] += w_ * bfu(v##k.z & 0xffffu); acc[5] += w_ * bfu(v##k.z >> 16); \
    acc[6] += w_ * bfu(v##k.w & 0xffffu); acc[7] += w_ * bfu(v##k.w >> 16); }

__global__ __launch_bounds__(256)
void k_agg(const unsigned short* __restrict__ hin, const int2* __restrict__ seg,
           const uint2* __restrict__ ev, const int* __restrict__ perm,
           unsigned short* __restrict__ outb) {
    int gid = blockIdx.x * 4 + (threadIdx.x >> 6);
    int lane = threadIdx.x & 63;
    if (gid >= N_NODES) return;
    int node = perm[gid];
    int2 se = seg[node];
    int e0 = se.x, e1 = se.y;
    float acc[8] = {0, 0, 0, 0, 0, 0, 0, 0};
    const unsigned short* base = hin + lane * 8;

    int e = e0;
    int n8 = e0 + ((e1 - e0) & ~7);
    for (; e < n8; e += 8) {
        LOADP(0); LOADP(1); LOADP(2); LOADP(3);
        LOADP(4); LOADP(5); LOADP(6); LOADP(7);
        LOADV(0); LOADV(1); LOADV(2); LOADV(3);
        LOADV(4); LOADV(5); LOADV(6); LOADV(7);
        ACCV(0); ACCV(1); ACCV(2); ACCV(3);
        ACCV(4); ACCV(5); ACCV(6); ACCV(7);
    }
    for (; e < e1; ++e) {
        LOADP(0); LOADV(0); ACCV(0);
    }

    uint4 o;
    o.x = (unsigned)f2b(acc[0]) | ((unsigned)f2b(acc[1]) << 16);
    o.y = (unsigned)f2b(acc[2]) | ((unsigned)f2b(acc[3]) << 16);
    o.z = (unsigned)f2b(acc[4]) | ((unsigned)f2b(acc[5]) << 16);
    o.w = (unsigned)f2b(acc[6]) | ((unsigned)f2b(acc[7]) << 16);
    *(uint4*)(outb + (size_t)node * F + lane * 8) = o;
}

extern "C" void kernel_launch(void* const* d_in, const int* in_sizes, int n_in,
                              void* d_out, int out_size, void* d_ws, size_t ws_size,
                              hipStream_t stream) {
    const float* x  = (const float*)d_in[0];
    const int*   ei = (const int*)d_in[1];
    const float* W1 = (const float*)d_in[2];
    const float* b1 = (const float*)d_in[3];
    const float* W2 = (const float*)d_in[4];
    const float* b2 = (const float*)d_in[5];
    float* out = (float*)d_out;

    char* ws = (char*)d_ws;
    size_t off = 0;
    auto alloc = [&](size_t bytes) -> void* {
        off = (off + 255) & ~(size_t)255;
        void* p = ws + off;
        off += bytes;
        return p;
    };

    unsigned short* tb   = (unsigned short*)alloc((size_t)N_NODES * F * 2); // agg out (bf16)
    unsigned short* W1t  = (unsigned short*)alloc((size_t)F * F * 2);
    unsigned short* W2t  = (unsigned short*)alloc((size_t)F * F * 2);
    unsigned int*   deg  = (unsigned int*)alloc((size_t)N_NODES * 4);
    float*          dis  = (float*)alloc((size_t)N_NODES * 4);
    int2*           seg  = (int2*)alloc((size_t)N_NODES * 8);
    unsigned int*   cur  = (unsigned int*)alloc((size_t)N_NODES * 4);
    unsigned int*   cnt  = (unsigned int*)alloc(256);
    unsigned int*   dcnt = (unsigned int*)alloc(64 * 4);
    unsigned int*   dcur = (unsigned int*)alloc(64 * 4);
    int*            perm = (int*)alloc((size_t)N_NODES * 4);
    uint2*          ev   = (uint2*)alloc((size_t)E_TOT * 8);

    // d_out doubles as scratch: lower half = h1 (bf16), upper half = x (bf16).
    unsigned short* h1b = (unsigned short*)d_out;
    unsigned short* xb  = (unsigned short*)((char*)d_out + (size_t)N_NODES * F * 2);

    int nb = (N_NODES + 255) / 256;

    k_init<<<nb, 256, 0, stream>>>(deg, cnt, dcnt);
    k_hist<<<(E_EDGES + 255) / 256, 256, 0, stream>>>(ei, deg);
    k_disalloc<<<nb, 256, 0, stream>>>(deg, cnt, dis, seg, cur, dcnt);
    k_dscan<<<1, 64, 0, stream>>>(dcnt, dcur);
    k_dperm<<<nb, 256, 0, stream>>>(deg, dcur, perm);
    k_scatter<<<(E_TOT + 255) / 256, 256, 0, stream>>>(ei, dis, cur, ev);

    k_cvtW<<<(2 * F * F) / 256, 256, 0, stream>>>(W1, W2, W1t, W2t);
    k_cvtX<<<(N_NODES * F / 8) / 256, 256, 0, stream>>>(x, xb);

    dim3 ggrid(4, (N_NODES + 255) / 256);   // 4 N-tiles innermost

    // layer 1: h1 = relu((A x) W1 + b1)   [reassociated]
    k_agg<<<(N_NODES + 3) / 4, 256, 0, stream>>>(xb, seg, ev, perm, tb);
    gemm_bt<<<ggrid, 512, 0, stream>>>(tb, W1t, b1, h1b, nullptr, 1, N_NODES);

    // layer 2: out = (A h1) W2 + b2       [reassociated]
    k_agg<<<(N_NODES + 3) / 4, 256, 0, stream>>>(h1b, seg, ev, perm, tb);
    gemm_bt<<<ggrid, 512, 0, stream>>>(tb, W2t, b2, nullptr, out, 0, N_NODES);
}

// Round 16
// 619.420 us; speedup vs baseline: 2.0975x; 2.0975x over previous
//
#include <hip/hip_runtime.h>

#define N_NODES 100000
#define E_EDGES 800000
#define E_TOT   900000
#define F 512

typedef __attribute__((ext_vector_type(8))) short short8;
typedef __attribute__((ext_vector_type(4))) float f32x4;
typedef unsigned int u32;

__device__ __forceinline__ float bfu(unsigned int u) {
    union { unsigned int i; float f; } c; c.i = u << 16; return c.f;
}
__device__ __forceinline__ unsigned short f2b(float f) {
    union { float f; unsigned int u; } c; c.f = f;
    return (unsigned short)((c.u + 0x7fffu + ((c.u >> 16) & 1u)) >> 16);
}
__device__ __forceinline__ float fbits(unsigned int u) {
    union { unsigned int i; float f; } c; c.i = u; return c.f;
}
__device__ __forceinline__ unsigned int bits(float f) {
    union { float f; unsigned int i; } c; c.f = f; return c.i;
}
__device__ __forceinline__ void gload_lds16(const void* g, void* l) {
    __builtin_amdgcn_global_load_lds(
        (const __attribute__((address_space(1))) u32*)g,
        (__attribute__((address_space(3))) u32*)l, 16, 0, 0);
}

// ---- CSR build ----
// deg starts zeroed (hipMemsetAsync); k_hist counts incoming edges;
// k_disalloc adds the self loop (+1) when sizing segments.
__global__ void k_hist(const int* __restrict__ ei, unsigned int* deg) {
    int e = blockIdx.x * 256 + threadIdx.x;
    if (e < E_EDGES) atomicAdd(&deg[ei[E_EDGES + e]], 1u);
}

__global__ void k_disalloc(const unsigned int* __restrict__ deg, unsigned int* counter,
                           float* __restrict__ dis,
                           int2* __restrict__ seg, unsigned int* __restrict__ cursor) {
    int i = blockIdx.x * 256 + threadIdx.x;
    if (i < N_NODES) {
        unsigned int d = deg[i] + 1u;             // + self loop
        dis[i] = rsqrtf((float)d);
        unsigned int p = atomicAdd(counter, d);
        seg[i] = make_int2((int)p, (int)(p + d));
        cursor[i] = p;
    }
}

__global__ void k_scatter(const int* __restrict__ ei, const float* __restrict__ dis,
                          unsigned int* __restrict__ cursor,
                          uint2* __restrict__ ev) {
    int e = blockIdx.x * 256 + threadIdx.x;
    if (e < E_TOT) {
        int s, d;
        if (e < E_EDGES) { s = ei[e]; d = ei[E_EDGES + e]; }
        else             { s = e - E_EDGES; d = s; }
        unsigned int p = atomicAdd(&cursor[d], 1u);
        ev[p] = make_uint2((unsigned)s, bits(dis[s] * dis[d]));
    }
}

// ---- dtype converts ----
__global__ void k_cvtX(const float* __restrict__ xin, unsigned short* __restrict__ xb) {
    int i = blockIdx.x * 256 + threadIdx.x;
    const f32x4* p = (const f32x4*)xin + (size_t)i * 2;
    f32x4 a = __builtin_nontemporal_load(p);
    f32x4 b = __builtin_nontemporal_load(p + 1);
    uint4 o;
    o.x = (unsigned)f2b(a[0]) | ((unsigned)f2b(a[1]) << 16);
    o.y = (unsigned)f2b(a[2]) | ((unsigned)f2b(a[3]) << 16);
    o.z = (unsigned)f2b(b[0]) | ((unsigned)f2b(b[1]) << 16);
    o.w = (unsigned)f2b(b[2]) | ((unsigned)f2b(b[3]) << 16);
    *(uint4*)(xb + (size_t)i * 8) = o;
}

__global__ void k_cvtW(const float* __restrict__ W1, const float* __restrict__ W2,
                       unsigned short* __restrict__ W1t, unsigned short* __restrict__ W2t) {
    int t = blockIdx.x * 256 + threadIdx.x;
    int which = t >= F * F;
    int u = t - which * F * F;
    int n = u >> 9, k = u & 511;
    const float* W = which ? W2 : W1;
    unsigned short* Wt = which ? W2t : W1t;
    Wt[u] = f2b(W[k * F + n]);
}

// ---- GEMM 256x128, BK=32, 2-phase dbuf, 48 KB LDS -> 2 blocks/CU ----
__global__ __launch_bounds__(512, 4)
void gemm_bt(const unsigned short* __restrict__ A, const unsigned short* __restrict__ Bt,
             const float* __restrict__ bias,
             unsigned short* __restrict__ outb, float* __restrict__ outf,
             int relu, int M) {
    __shared__ unsigned short sm[24576];  // 48 KB: A0@0, A1@8192, B0@16384, B1@20480

    // bijective XCD remap: 4 N-siblings of one A-slab -> same XCD, adjacent
    int nwg = gridDim.x * gridDim.y;              // 1564
    int orig = blockIdx.y * gridDim.x + blockIdx.x;
    int q = nwg >> 3, r = nwg & 7;
    int xcd = orig & 7, j8 = orig >> 3;
    int wgid = (xcd < r ? xcd * (q + 1) : r * (q + 1) + (xcd - r) * q) + j8;
    int by = wgid & 3;                            // N tile (0..3), 128 cols
    int bx = wgid >> 2;                           // M tile (0..390)

    int t  = threadIdx.x;
    int lane = t & 63, w = t >> 6;
    int wr = w >> 1, wc = w & 1;
    int rsel = lane & 15, khalf = (lane >> 4) * 8;

    f32x4 acc[4][4];
    #pragma unroll
    for (int m = 0; m < 4; ++m)
        #pragma unroll
        for (int n = 0; n < 4; ++n)
            acc[m][n] = (f32x4){0.f, 0.f, 0.f, 0.f};

    int rowBase = bx * 256;

    int arA[2], kcA[2];
    #pragma unroll
    for (int i = 0; i < 2; ++i) {
        int idx = i * 512 + t;
        int rr = idx >> 2;
        kcA[i] = (idx & 3) * 8;
        int ga = rowBase + rr; if (ga >= M) ga = M - 1;
        arA[i] = ga;
    }
    int brB = by * 128 + (t >> 2);
    int kcB = (t & 3) * 8;

    auto STAGE = [&](int buf, int k0) {
        gload_lds16(A + (size_t)arA[0] * F + k0 + kcA[0], sm + buf * 8192 + t * 8);
        gload_lds16(A + (size_t)arA[1] * F + k0 + kcA[1], sm + buf * 8192 + (512 + t) * 8);
        gload_lds16(Bt + (size_t)brB * F + k0 + kcB, sm + 16384 + buf * 4096 + t * 8);
    };
    auto COMPUTE = [&](int buf) {
        const unsigned short* la = sm + buf * 8192;
        const unsigned short* lb = sm + 16384 + buf * 4096;
        short8 bfr[4];
        #pragma unroll
        for (int n = 0; n < 4; ++n)
            bfr[n] = *(const short8*)&lb[(wc * 64 + n * 16 + rsel) * 32 + khalf];
        #pragma unroll
        for (int m = 0; m < 4; ++m) {
            short8 af = *(const short8*)&la[(wr * 64 + m * 16 + rsel) * 32 + khalf];
            #pragma unroll
            for (int n = 0; n < 4; ++n)
                acc[m][n] = __builtin_amdgcn_mfma_f32_16x16x32_bf16(af, bfr[n], acc[m][n], 0, 0, 0);
        }
    };

    STAGE(0, 0);
    __syncthreads();
    #pragma unroll
    for (int kp = 0; kp < 8; ++kp) {
        STAGE(1, (2 * kp + 1) * 32);
        COMPUTE(0);
        __syncthreads();
        if (kp < 7) STAGE(0, (2 * kp + 2) * 32);
        COMPUTE(1);
        __syncthreads();
    }

    int rq = (lane >> 4) * 4, cq = lane & 15;
    if (outb) {
        // restage bf16 C-tile through LDS in two 128x128 halves
        #pragma unroll
        for (int h = 0; h < 2; ++h) {
            if (h) __syncthreads();
            if ((wr >> 1) == h) {
                #pragma unroll
                for (int m = 0; m < 4; ++m)
                    #pragma unroll
                    for (int n = 0; n < 4; ++n) {
                        int cl = wc * 64 + n * 16 + cq;
                        float bv = bias[by * 128 + cl];
                        #pragma unroll
                        for (int j = 0; j < 4; ++j) {
                            int rl = (wr & 1) * 64 + m * 16 + rq + j;
                            float v = acc[m][n][j] + bv;
                            if (relu) v = fmaxf(v, 0.f);
                            sm[rl * 128 + cl] = f2b(v);
                        }
                    }
            }
            __syncthreads();
            // 128x128 half = 16384 shorts = 512 threads x 4 x 8
            #pragma unroll
            for (int p = 0; p < 4; ++p) {
                int sidx = (p * 512 + t) * 8;
                int row = sidx >> 7;
                int col = sidx & 127;
                int grow = rowBase + h * 128 + row;
                if (grow < M) {
                    uint4 v = *(const uint4*)&sm[sidx];
                    *(uint4*)&outb[(size_t)grow * F + by * 128 + col] = v;
                }
            }
        }
    } else {
        #pragma unroll
        for (int m = 0; m < 4; ++m)
            #pragma unroll
            for (int n = 0; n < 4; ++n) {
                int colv = by * 128 + wc * 64 + n * 16 + cq;
                float bv = bias[colv];
                #pragma unroll
                for (int j = 0; j < 4; ++j) {
                    int row = rowBase + wr * 64 + m * 16 + rq + j;
                    if (row < M) {
                        float v = acc[m][n][j] + bv;
                        if (relu) v = fmaxf(v, 0.f);
                        __builtin_nontemporal_store(v, outf + (size_t)row * F + colv);
                    }
                }
            }
    }
}

// ---- aggregation: g[d] = sum_e val[e] * hin[col[e]]  (512-wide, x8 unroll) ----
#define LOADP(k) uint2 p##k = ev[e + k]
#define LOADV(k) uint4 v##k = *(const uint4*)(base + ((size_t)p##k.x << 9))
#define ACCV(k)  { float w_ = fbits(p##k.y); \
    acc[0] += w_ * bfu(v##k.x & 0xffffu); acc[1] += w_ * bfu(v##k.x >> 16); \
    acc[2] += w_ * bfu(v##k.y & 0xffffu); acc[3] += w_ * bfu(v##k.y >> 16); \
    acc[4] += w_ * bfu(v##k.z & 0xffffu); acc[5] += w_ * bfu(v##k.z >> 16); \
    acc[6] += w_ * bfu(v##k.w & 0xffffu); acc[7] += w_ * bfu(v##k.w >> 16); }

__global__ __launch_bounds__(256)
void k_agg(const unsigned short* __restrict__ hin, const int2* __restrict__ seg,
           const uint2* __restrict__ ev,
           unsigned short* __restrict__ outb) {
    int node = blockIdx.x * 4 + (threadIdx.x >> 6);
    int lane = threadIdx.x & 63;
    if (node >= N_NODES) return;
    int2 se = seg[node];
    int e0 = se.x, e1 = se.y;
    float acc[8] = {0, 0, 0, 0, 0, 0, 0, 0};
    const unsigned short* base = hin + lane * 8;

    int e = e0;
    int n8 = e0 + ((e1 - e0) & ~7);
    for (; e < n8; e += 8) {
        LOADP(0); LOADP(1); LOADP(2); LOADP(3);
        LOADP(4); LOADP(5); LOADP(6); LOADP(7);
        LOADV(0); LOADV(1); LOADV(2); LOADV(3);
        LOADV(4); LOADV(5); LOADV(6); LOADV(7);
        ACCV(0); ACCV(1); ACCV(2); ACCV(3);
        ACCV(4); ACCV(5); ACCV(6); ACCV(7);
    }
    for (; e < e1; ++e) {
        LOADP(0); LOADV(0); ACCV(0);
    }

    uint4 o;
    o.x = (unsigned)f2b(acc[0]) | ((unsigned)f2b(acc[1]) << 16);
    o.y = (unsigned)f2b(acc[2]) | ((unsigned)f2b(acc[3]) << 16);
    o.z = (unsigned)f2b(acc[4]) | ((unsigned)f2b(acc[5]) << 16);
    o.w = (unsigned)f2b(acc[6]) | ((unsigned)f2b(acc[7]) << 16);
    *(uint4*)(outb + (size_t)node * F + lane * 8) = o;
}

extern "C" void kernel_launch(void* const* d_in, const int* in_sizes, int n_in,
                              void* d_out, int out_size, void* d_ws, size_t ws_size,
                              hipStream_t stream) {
    const float* x  = (const float*)d_in[0];
    const int*   ei = (const int*)d_in[1];
    const float* W1 = (const float*)d_in[2];
    const float* b1 = (const float*)d_in[3];
    const float* W2 = (const float*)d_in[4];
    const float* b2 = (const float*)d_in[5];
    float* out = (float*)d_out;

    char* ws = (char*)d_ws;
    size_t off = 0;
    auto alloc = [&](size_t bytes) -> void* {
        off = (off + 255) & ~(size_t)255;
        void* p = ws + off;
        off += bytes;
        return p;
    };

    unsigned short* tb  = (unsigned short*)alloc((size_t)N_NODES * F * 2); // agg out (bf16)
    unsigned short* W1t = (unsigned short*)alloc((size_t)F * F * 2);
    unsigned short* W2t = (unsigned short*)alloc((size_t)F * F * 2);
    unsigned int*   deg = (unsigned int*)alloc((size_t)N_NODES * 4);
    unsigned int*   cnt = (unsigned int*)alloc(256);
    float*          dis = (float*)alloc((size_t)N_NODES * 4);
    int2*           seg = (int2*)alloc((size_t)N_NODES * 8);
    unsigned int*   cur = (unsigned int*)alloc((size_t)N_NODES * 4);
    uint2*          ev  = (uint2*)alloc((size_t)E_TOT * 8);

    // d_out doubles as scratch: lower half = h1 (bf16), upper half = x (bf16).
    unsigned short* h1b = (unsigned short*)d_out;
    unsigned short* xb  = (unsigned short*)((char*)d_out + (size_t)N_NODES * F * 2);

    int nb = (N_NODES + 255) / 256;

    hipMemsetAsync(deg, 0, (size_t)N_NODES * 4, stream);
    hipMemsetAsync(cnt, 0, 4, stream);
    k_hist<<<(E_EDGES + 255) / 256, 256, 0, stream>>>(ei, deg);
    k_disalloc<<<nb, 256, 0, stream>>>(deg, cnt, dis, seg, cur);
    k_scatter<<<(E_TOT + 255) / 256, 256, 0, stream>>>(ei, dis, cur, ev);

    k_cvtW<<<(2 * F * F) / 256, 256, 0, stream>>>(W1, W2, W1t, W2t);
    k_cvtX<<<(N_NODES * F / 8) / 256, 256, 0, stream>>>(x, xb);

    dim3 ggrid(4, (N_NODES + 255) / 256);   // 4 N-tiles innermost

    // layer 1: h1 = relu((A x) W1 + b1)   [reassociated]
    k_agg<<<(N_NODES + 3) / 4, 256, 0, stream>>>(xb, seg, ev, tb);
    gemm_bt<<<ggrid, 512, 0, stream>>>(tb, W1t, b1, h1b, nullptr, 1, N_NODES);

    // layer 2: out = (A h1) W2 + b2       [reassociated]
    k_agg<<<(N_NODES + 3) / 4, 256, 0, stream>>>(h1b, seg, ev, tb);
    gemm_bt<<<ggrid, 512, 0, stream>>>(tb, W2t, b2, nullptr, out, 0, N_NODES);
}

// Round 19
// 615.035 us; speedup vs baseline: 2.1125x; 1.0071x over previous
//
#include <hip/hip_runtime.h>

#define N_NODES 100000
#define E_EDGES 800000
#define E_TOT   900000
#define F 512

typedef __attribute__((ext_vector_type(8))) short short8;
typedef __attribute__((ext_vector_type(4))) float f32x4;
typedef unsigned int u32;

__device__ __forceinline__ float bfu(unsigned int u) {
    union { unsigned int i; float f; } c; c.i = u << 16; return c.f;
}
__device__ __forceinline__ unsigned short f2b(float f) {
    union { float f; unsigned int u; } c; c.f = f;
    return (unsigned short)((c.u + 0x7fffu + ((c.u >> 16) & 1u)) >> 16);
}
__device__ __forceinline__ float fbits(unsigned int u) {
    union { unsigned int i; float f; } c; c.i = u; return c.f;
}
__device__ __forceinline__ unsigned int bits(float f) {
    union { float f; unsigned int i; } c; c.f = f; return c.i;
}
__device__ __forceinline__ void gload_lds16(const void* g, void* l) {
    __builtin_amdgcn_global_load_lds(
        (const __attribute__((address_space(1))) u32*)g,
        (__attribute__((address_space(3))) u32*)l, 16, 0, 0);
}

// ---- CSR build ----
__global__ void k_hist(const int* __restrict__ ei, unsigned int* deg) {
    int e = blockIdx.x * 256 + threadIdx.x;
    if (e < E_EDGES) atomicAdd(&deg[ei[E_EDGES + e]], 1u);
}

__global__ void k_disalloc(const unsigned int* __restrict__ deg, unsigned int* counter,
                           float* __restrict__ dis,
                           int2* __restrict__ seg, unsigned int* __restrict__ cursor) {
    int i = blockIdx.x * 256 + threadIdx.x;
    if (i < N_NODES) {
        unsigned int d = deg[i] + 1u;             // + self loop
        dis[i] = rsqrtf((float)d);
        unsigned int p = atomicAdd(counter, d);
        seg[i] = make_int2((int)p, (int)(p + d));
        cursor[i] = p;
    }
}

__global__ void k_scatter(const int* __restrict__ ei, const float* __restrict__ dis,
                          unsigned int* __restrict__ cursor,
                          uint2* __restrict__ ev) {
    int e = blockIdx.x * 256 + threadIdx.x;
    if (e < E_TOT) {
        int s, d;
        if (e < E_EDGES) { s = ei[e]; d = ei[E_EDGES + e]; }
        else             { s = e - E_EDGES; d = s; }
        unsigned int p = atomicAdd(&cursor[d], 1u);
        ev[p] = make_uint2((unsigned)s, bits(dis[s] * dis[d]));
    }
}

// ---- dtype converts ----
__global__ void k_cvtX(const float* __restrict__ xin, unsigned short* __restrict__ xb) {
    int i = blockIdx.x * 256 + threadIdx.x;
    const f32x4* p = (const f32x4*)xin + (size_t)i * 2;
    f32x4 a = __builtin_nontemporal_load(p);
    f32x4 b = __builtin_nontemporal_load(p + 1);
    uint4 o;
    o.x = (unsigned)f2b(a[0]) | ((unsigned)f2b(a[1]) << 16);
    o.y = (unsigned)f2b(a[2]) | ((unsigned)f2b(a[3]) << 16);
    o.z = (unsigned)f2b(b[0]) | ((unsigned)f2b(b[1]) << 16);
    o.w = (unsigned)f2b(b[2]) | ((unsigned)f2b(b[3]) << 16);
    *(uint4*)(xb + (size_t)i * 8) = o;
}

__global__ void k_cvtW(const float* __restrict__ W1, const float* __restrict__ W2,
                       unsigned short* __restrict__ W1t, unsigned short* __restrict__ W2t) {
    int t = blockIdx.x * 256 + threadIdx.x;
    int which = t >= F * F;
    int u = t - which * F * F;
    int n = u >> 9, k = u & 511;
    const float* W = which ? W2 : W1;
    unsigned short* Wt = which ? W2t : W1t;
    Wt[u] = f2b(W[k * F + n]);
}

// ---- GEMM 128x128, BK=64, counted-vmcnt 2-phase, 64 KB LDS -> 2 blocks/CU ----
// 256 threads = 4 waves (2M x 2N); per-wave 64x64 (acc[4][4]).
// Per K-tile: phase0 stages A(t+1) [4 loads] then vmcnt(4) (all of tile t
// retired; only A(t+1) outstanding); phase1 stages B(t+1), no wait.
// Last tile: vmcnt(0). LDS swizzle: involution col^16sh when row&4 (round-11
// verified pair: pre-swizzled source + XOR'd read).

#define G_STAGE_A(BUF, K0) { _Pragma("unroll") \
    for (int i_ = 0; i_ < 4; ++i_) { \
        int idx_ = i_ * 256 + t; \
        gload_lds16(A + (size_t)arA[i_] * F + (K0) + kcsA[i_], sm + (BUF) * 8192 + idx_ * 8); \
    } }
#define G_STAGE_B(BUF, K0) { _Pragma("unroll") \
    for (int i_ = 0; i_ < 4; ++i_) { \
        int idx_ = i_ * 256 + t; \
        gload_lds16(Bt + (size_t)brB[i_] * F + (K0) + kcsB[i_], sm + 16384 + (BUF) * 8192 + idx_ * 8); \
    } }

#define G_PHASE(BUF, KS, WLIT, DOWAIT, DOSTAGE, K0N) { \
    if (DOSTAGE) { if ((KS) == 0) { G_STAGE_A((BUF) ^ 1, K0N) } else { G_STAGE_B((BUF) ^ 1, K0N) } } \
    if (DOWAIT) { asm volatile("s_waitcnt vmcnt(" #WLIT ")" ::: "memory"); } \
    __builtin_amdgcn_s_barrier(); \
    asm volatile("" ::: "memory"); \
    { \
        const unsigned short* la = sm + (BUF) * 8192; \
        const unsigned short* lb = sm + 16384 + (BUF) * 8192; \
        int koff = ((KS) * 32 + khalf) ^ kx; \
        short8 af_[4], bf_[4]; \
        _Pragma("unroll") \
        for (int m_ = 0; m_ < 4; ++m_) \
            af_[m_] = *(const short8*)&la[(wr * 64 + m_ * 16 + rsel) * 64 + koff]; \
        _Pragma("unroll") \
        for (int n_ = 0; n_ < 4; ++n_) \
            bf_[n_] = *(const short8*)&lb[(wc * 64 + n_ * 16 + rsel) * 64 + koff]; \
        __builtin_amdgcn_s_setprio(1); \
        _Pragma("unroll") \
        for (int m_ = 0; m_ < 4; ++m_) \
            _Pragma("unroll") \
            for (int n_ = 0; n_ < 4; ++n_) \
                acc[m_][n_] = __builtin_amdgcn_mfma_f32_16x16x32_bf16(af_[m_], bf_[n_], acc[m_][n_], 0, 0, 0); \
        __builtin_amdgcn_s_setprio(0); \
    } \
    __builtin_amdgcn_s_barrier(); }

#define G_KTILE(BUF, K0N) \
    G_PHASE(BUF, 0, 4, 1, 1, K0N) G_PHASE(BUF, 1, 8, 0, 1, K0N)

__global__ __launch_bounds__(256, 2)
void gemm_bt(const unsigned short* __restrict__ A, const unsigned short* __restrict__ Bt,
             const float* __restrict__ bias,
             unsigned short* __restrict__ outb, float* __restrict__ outf,
             int relu, int M) {
    __shared__ unsigned short sm[32768];  // 64 KB: A0@0, A1@8192, B0@16384, B1@24576

    // bijective XCD remap: 4 N-siblings of one A-slab -> same XCD, adjacent
    int nwg = gridDim.x * gridDim.y;              // 3128
    int orig = blockIdx.y * gridDim.x + blockIdx.x;
    int q = nwg >> 3, r = nwg & 7;
    int xcd = orig & 7, j8 = orig >> 3;
    int wgid = (xcd < r ? xcd * (q + 1) : r * (q + 1) + (xcd - r) * q) + j8;
    int by = wgid & 3;                            // N tile (0..3), 128 cols
    int bx = wgid >> 2;                           // M tile (0..781)

    int t  = threadIdx.x;
    int lane = t & 63, w = t >> 6;
    int wr = w >> 1, wc = w & 1;                  // 2x2 waves
    int rsel = lane & 15, khalf = (lane >> 4) * 8;
    int kx = (lane & 4) ? 16 : 0;                 // read-side swizzle XOR (shorts)

    f32x4 acc[4][4];
    #pragma unroll
    for (int m = 0; m < 4; ++m)
        #pragma unroll
        for (int n = 0; n < 4; ++n)
            acc[m][n] = (f32x4){0.f, 0.f, 0.f, 0.f};

    int rowBase = bx * 128;

    // staging coords: A tile 128x64 = 1024 16B-chunks, 4/thread.
    // chunk idx: row = idx>>3 (0..127), colbase = (idx&7)*8 shorts.
    // source pre-swizzle: col ^16 shorts when row&4 (involution; LDS dest linear)
    int arA[4], kcsA[4], brB[4], kcsB[4];
    #pragma unroll
    for (int i = 0; i < 4; ++i) {
        int idx = i * 256 + t;
        int rr = idx >> 3;
        int kc = (idx & 7) * 8;
        int kcs = kc ^ ((rr & 4) ? 16 : 0);
        int ga = rowBase + rr; if (ga >= M) ga = M - 1;
        arA[i] = ga;  kcsA[i] = kcs;
        brB[i] = by * 128 + rr;  kcsB[i] = kcs;
    }

    // prologue: stage tile 0 (A then B) into buf0
    G_STAGE_A(0, 0) G_STAGE_B(0, 0)

    // K = 512 = 8 tiles of 64; tile t in buf(t&1); tiles 0..6 prefetch t+1
    G_KTILE(0,  64) G_KTILE(1, 128) G_KTILE(0, 192) G_KTILE(1, 256)
    G_KTILE(0, 320) G_KTILE(1, 384) G_KTILE(0, 448)
    // last tile: drain, no staging
    G_PHASE(1, 0, 0, 1, 0, 0) G_PHASE(1, 1, 0, 0, 0, 0)

    int rq = (lane >> 4) * 4, cq = lane & 15;
    if (outb) {
        // restage bf16 C-tile (128x128 = 32 KB) through LDS, coalesced out
        #pragma unroll
        for (int m = 0; m < 4; ++m)
            #pragma unroll
            for (int n = 0; n < 4; ++n) {
                int cl = wc * 64 + n * 16 + cq;
                float bv = bias[by * 128 + cl];
                #pragma unroll
                for (int j = 0; j < 4; ++j) {
                    int rl = wr * 64 + m * 16 + rq + j;
                    float v = acc[m][n][j] + bv;
                    if (relu) v = fmaxf(v, 0.f);
                    sm[rl * 128 + cl] = f2b(v);
                }
            }
        __syncthreads();
        // 128x128 = 16384 shorts = 256 threads x 8 x 8
        #pragma unroll
        for (int p = 0; p < 8; ++p) {
            int sidx = (p * 256 + t) * 8;
            int row = sidx >> 7;
            int col = sidx & 127;
            int grow = rowBase + row;
            if (grow < M) {
                uint4 v = *(const uint4*)&sm[sidx];
                *(uint4*)&outb[(size_t)grow * F + by * 128 + col] = v;
            }
        }
    } else {
        #pragma unroll
        for (int m = 0; m < 4; ++m)
            #pragma unroll
            for (int n = 0; n < 4; ++n) {
                int colv = by * 128 + wc * 64 + n * 16 + cq;
                float bv = bias[colv];
                #pragma unroll
                for (int j = 0; j < 4; ++j) {
                    int row = rowBase + wr * 64 + m * 16 + rq + j;
                    if (row < M) {
                        float v = acc[m][n][j] + bv;
                        if (relu) v = fmaxf(v, 0.f);
                        __builtin_nontemporal_store(v, outf + (size_t)row * F + colv);
                    }
                }
            }
    }
}

// ---- aggregation: g[d] = sum_e val[e] * hin[col[e]]  (512-wide, x8 unroll) ----
#define LOADP(k) uint2 p##k = ev[e + k]
#define LOADV(k) uint4 v##k = *(const uint4*)(base + ((size_t)p##k.x << 9))
#define ACCV(k)  { float w_ = fbits(p##k.y); \
    acc[0] += w_ * bfu(v##k.x & 0xffffu); acc[1] += w_ * bfu(v##k.x >> 16); \
    acc[2] += w_ * bfu(v##k.y & 0xffffu); acc[3] += w_ * bfu(v##k.y >> 16); \
    acc[4] += w_ * bfu(v##k.z & 0xffffu); acc[5] += w_ * bfu(v##k.z >> 16); \
    acc[6] += w_ * bfu(v##k.w & 0xffffu); acc[7] += w_ * bfu(v##k.w >> 16); }

__global__ __launch_bounds__(256)
void k_agg(const unsigned short* __restrict__ hin, const int2* __restrict__ seg,
           const uint2* __restrict__ ev,
           unsigned short* __restrict__ outb) {
    int node = blockIdx.x * 4 + (threadIdx.x >> 6);
    int lane = threadIdx.x & 63;
    if (node >= N_NODES) return;
    int2 se = seg[node];
    int e0 = se.x, e1 = se.y;
    float acc[8] = {0, 0, 0, 0, 0, 0, 0, 0};
    const unsigned short* base = hin + lane * 8;

    int e = e0;
    int n8 = e0 + ((e1 - e0) & ~7);
    for (; e < n8; e += 8) {
        LOADP(0); LOADP(1); LOADP(2); LOADP(3);
        LOADP(4); LOADP(5); LOADP(6); LOADP(7);
        LOADV(0); LOADV(1); LOADV(2); LOADV(3);
        LOADV(4); LOADV(5); LOADV(6); LOADV(7);
        ACCV(0); ACCV(1); ACCV(2); ACCV(3);
        ACCV(4); ACCV(5); ACCV(6); ACCV(7);
    }
    for (; e < e1; ++e) {
        LOADP(0); LOADV(0); ACCV(0);
    }

    uint4 o;
    o.x = (unsigned)f2b(acc[0]) | ((unsigned)f2b(acc[1]) << 16);
    o.y = (unsigned)f2b(acc[2]) | ((unsigned)f2b(acc[3]) << 16);
    o.z = (unsigned)f2b(acc[4]) | ((unsigned)f2b(acc[5]) << 16);
    o.w = (unsigned)f2b(acc[6]) | ((unsigned)f2b(acc[7]) << 16);
    *(uint4*)(outb + (size_t)node * F + lane * 8) = o;
}

extern "C" void kernel_launch(void* const* d_in, const int* in_sizes, int n_in,
                              void* d_out, int out_size, void* d_ws, size_t ws_size,
                              hipStream_t stream) {
    const float* x  = (const float*)d_in[0];
    const int*   ei = (const int*)d_in[1];
    const float* W1 = (const float*)d_in[2];
    const float* b1 = (const float*)d_in[3];
    const float* W2 = (const float*)d_in[4];
    const float* b2 = (const float*)d_in[5];
    float* out = (float*)d_out;

    char* ws = (char*)d_ws;
    size_t off = 0;
    auto alloc = [&](size_t bytes) -> void* {
        off = (off + 255) & ~(size_t)255;
        void* p = ws + off;
        off += bytes;
        return p;
    };

    unsigned short* tb  = (unsigned short*)alloc((size_t)N_NODES * F * 2); // agg out (bf16)
    unsigned short* W1t = (unsigned short*)alloc((size_t)F * F * 2);
    unsigned short* W2t = (unsigned short*)alloc((size_t)F * F * 2);
    unsigned int*   deg = (unsigned int*)alloc((size_t)N_NODES * 4);
    unsigned int*   cnt = (unsigned int*)alloc(256);
    float*          dis = (float*)alloc((size_t)N_NODES * 4);
    int2*           seg = (int2*)alloc((size_t)N_NODES * 8);
    unsigned int*   cur = (unsigned int*)alloc((size_t)N_NODES * 4);
    uint2*          ev  = (uint2*)alloc((size_t)E_TOT * 8);

    // d_out doubles as scratch: lower half = h1 (bf16), upper half = x (bf16).
    unsigned short* h1b = (unsigned short*)d_out;
    unsigned short* xb  = (unsigned short*)((char*)d_out + (size_t)N_NODES * F * 2);

    int nb = (N_NODES + 255) / 256;

    hipMemsetAsync(deg, 0, (size_t)N_NODES * 4, stream);
    hipMemsetAsync(cnt, 0, 4, stream);
    k_hist<<<(E_EDGES + 255) / 256, 256, 0, stream>>>(ei, deg);
    k_disalloc<<<nb, 256, 0, stream>>>(deg, cnt, dis, seg, cur);
    k_scatter<<<(E_TOT + 255) / 256, 256, 0, stream>>>(ei, dis, cur, ev);

    k_cvtW<<<(2 * F * F) / 256, 256, 0, stream>>>(W1, W2, W1t, W2t);
    k_cvtX<<<(N_NODES * F / 8) / 256, 256, 0, stream>>>(x, xb);

    dim3 ggrid(4, (N_NODES + 127) / 128);   // 4 N-tiles innermost, 782 M-tiles

    // layer 1: h1 = relu((A x) W1 + b1)   [reassociated]
    k_agg<<<(N_NODES + 3) / 4, 256, 0, stream>>>(xb, seg, ev, tb);
    gemm_bt<<<ggrid, 256, 0, stream>>>(tb, W1t, b1, h1b, nullptr, 1, N_NODES);

    // layer 2: out = (A h1) W2 + b2       [reassociated]
    k_agg<<<(N_NODES + 3) / 4, 256, 0, stream>>>(h1b, seg, ev, tb);
    gemm_bt<<<ggrid, 256, 0, stream>>>(tb, W2t, b2, nullptr, out, 0, N_NODES);
}